// Round 1
// baseline (249.787 us; speedup 1.0000x reference)
//
#include <hip/hip_runtime.h>
#include <hip/hip_fp16.h>

// VGAE GCN encoder, pull-based. Pipeline (memset + 3 kernels):
//   1 partition  : single-pass CSR build. Coarse buckets = 256 nodes (NB=391),
//                  fixed-capacity segments (CAP=6144). 512 blocks (chunk=3128,
//                  2 blocks/CU): per block LDS hist of its chunk -> one global
//                  atomicAdd per bucket reserves range -> rank+stage whole
//                  chunk in LDS -> bucket-major write (contiguous ~8-edge
//                  runs). Packed int: (d&255)<<17 | s  (needs N < 2^17).
//                  Also preps W^T fp16.
//   2 gemm       : Hs = fp16((x @ [Wmu|Wls]) * dinv) MFMA 16x16x32_f16;
//                  2 blocks per coarse bucket; deg from filtered segment hist.
//   3 sort_gather: 4 blocks per coarse bucket (64-node quadrants, 512 thr =
//                  8 waves x 8 nodes): filter+fine-sort segment in LDS ->
//                  per-node src lists, wave gathers 2 nodes at a time with a
//                  2x-unrolled edge loop (4 uint4 gathers in flight/lane),
//                  packed fp16 adds, shared 16-lane reparam epilogue.

#define CIN  128
#define CCAT 128
#define COUT 64
#define MAX_LOGSTD 10.0f

#define CB_SHIFT 8             // 256 nodes per coarse bucket
#define CAP      6144          // segment capacity (mean 4092, +32 sd)
#define PART_G   512
#define PART_T   512
#define CHUNK_MAX 3200         // LDS staging capacity (chunk = 3128)
#define SORT_CAP 1536          // fine staging (mean 1023, +16 sd)
#define CSRG_CAP 2048          // global fallback region per fine block

typedef _Float16 half8 __attribute__((ext_vector_type(8)));
typedef float floatx4 __attribute__((ext_vector_type(4)));

#define WT_STRIDE 136          // fp16 elems; 272 B rows keep 16B alignment

__device__ __forceinline__ __half2 h2shfl_xor(__half2 v, int m) {
    union { __half2 h; int i; } u; u.h = v;
    u.i = __shfl_xor(u.i, m, 64);
    return u.h;
}

// ---------------- 1: single-pass partition + W^T prep ----------------------
__global__ __launch_bounds__(PART_T) void partition_kernel(
    const int* __restrict__ src, const int* __restrict__ dst,
    int* __restrict__ resv, int* __restrict__ pairs,
    const float* __restrict__ Wmu, const float* __restrict__ Wls,
    __half* __restrict__ Wtg, int E, int NBC, int chunk)
{
    __shared__ int hist[512];
    __shared__ int scs [512];
    __shared__ int lcur[512];
    __shared__ int base[512];
    __shared__ int ssort[CHUNK_MAX];
    __shared__ unsigned short sbuck[CHUNK_MAX];

    const int t = threadIdx.x, g = blockIdx.x;
    // W^T prep on first 32 blocks: Wtg[c*128+k] = W[k][c]
    if (g < 32) {
        int idx = g * PART_T + t;          // 0..16383
        int c = idx >> 7, k = idx & 127;
        float v = (c < 64) ? Wmu[k * COUT + c] : Wls[k * COUT + (c - 64)];
        Wtg[c * 128 + k] = __float2half(v);
    }
    hist[t] = 0;
    __syncthreads();

    const int lo  = g * chunk;
    const int hi  = min(E, lo + chunk);
    const int cnt = (hi > lo) ? (hi - lo) : 0;
    const bool al = ((((uintptr_t)(dst + lo)) | ((uintptr_t)(src + lo))) & 15) == 0;

    // pass 1: LDS histogram of dst buckets
    if (cnt > 0 && al) {
        const int nb4 = cnt >> 2;
        const int4* d4 = (const int4*)(dst + lo);
        for (int i = t; i < nb4; i += PART_T) {
            int4 d = d4[i];
            atomicAdd(&hist[d.x >> CB_SHIFT], 1);
            atomicAdd(&hist[d.y >> CB_SHIFT], 1);
            atomicAdd(&hist[d.z >> CB_SHIFT], 1);
            atomicAdd(&hist[d.w >> CB_SHIFT], 1);
        }
        for (int e = lo + (nb4 << 2) + t; e < hi; e += PART_T)
            atomicAdd(&hist[dst[e] >> CB_SHIFT], 1);
    } else if (cnt > 0) {
        for (int e = lo + t; e < hi; e += PART_T)
            atomicAdd(&hist[dst[e] >> CB_SHIFT], 1);
    }
    __syncthreads();

    // reserve global ranges; inclusive scan of hist for LDS slots
    scs[t]  = hist[t];
    lcur[t] = 0;
    base[t] = (t < NBC && hist[t] > 0) ? atomicAdd(&resv[t], hist[t]) : 0;
    __syncthreads();
    for (int off = 1; off < 512; off <<= 1) {
        int v = (t >= off) ? scs[t - off] : 0;
        __syncthreads();
        scs[t] += v;
        __syncthreads();
    }

    // pass 2: rank + stage packed edges into LDS (bucket-major)
    if (cnt > 0 && al) {
        const int nb4 = cnt >> 2;
        const int4* d4 = (const int4*)(dst + lo);
        const int4* s4 = (const int4*)(src + lo);
        for (int i = t; i < nb4; i += PART_T) {
            int4 d = d4[i]; int4 s = s4[i];
            int b, r, slot;
            b = d.x >> CB_SHIFT; r = atomicAdd(&lcur[b], 1); slot = scs[b] - hist[b] + r;
            ssort[slot] = ((d.x & 255) << 17) | s.x; sbuck[slot] = (unsigned short)b;
            b = d.y >> CB_SHIFT; r = atomicAdd(&lcur[b], 1); slot = scs[b] - hist[b] + r;
            ssort[slot] = ((d.y & 255) << 17) | s.y; sbuck[slot] = (unsigned short)b;
            b = d.z >> CB_SHIFT; r = atomicAdd(&lcur[b], 1); slot = scs[b] - hist[b] + r;
            ssort[slot] = ((d.z & 255) << 17) | s.z; sbuck[slot] = (unsigned short)b;
            b = d.w >> CB_SHIFT; r = atomicAdd(&lcur[b], 1); slot = scs[b] - hist[b] + r;
            ssort[slot] = ((d.w & 255) << 17) | s.w; sbuck[slot] = (unsigned short)b;
        }
        for (int e = lo + (nb4 << 2) + t; e < hi; e += PART_T) {
            int d = dst[e], s = src[e];
            int b = d >> CB_SHIFT;
            int r = atomicAdd(&lcur[b], 1);
            int slot = scs[b] - hist[b] + r;
            ssort[slot] = ((d & 255) << 17) | s; sbuck[slot] = (unsigned short)b;
        }
    } else if (cnt > 0) {
        for (int e = lo + t; e < hi; e += PART_T) {
            int d = dst[e], s = src[e];
            int b = d >> CB_SHIFT;
            int r = atomicAdd(&lcur[b], 1);
            int slot = scs[b] - hist[b] + r;
            ssort[slot] = ((d & 255) << 17) | s; sbuck[slot] = (unsigned short)b;
        }
    }
    __syncthreads();

    // pass 3: bucket-major write -> contiguous runs, coalesced
    for (int i = t; i < cnt; i += PART_T) {
        int b = sbuck[i];
        int gofs = base[b] + (i - (scs[b] - hist[b]));
        if (gofs < CAP)   // memory-safety clamp (statistically unreachable)
            pairs[(size_t)b * CAP + gofs] = ssort[i];
    }
}

// ---------------- 2: MFMA GEMM, 2 blocks per coarse bucket -----------------
// 512 thr = 8 waves x 16 rows = 128 rows/block. Wt staged from global fp16;
// A-frags direct from x; deg from filtered segment histogram.
__global__ __launch_bounds__(512) void gemm_scale_kernel(
    const float* __restrict__ x,
    const __half* __restrict__ Wtg,
    const int* __restrict__ resv, const int* __restrict__ pairs,
    __half* __restrict__ Hs, int N, int NBC)
{
    __shared__ _Float16 Wt[128 * WT_STRIDE];
    __shared__ int dhist[128];

    const int t    = threadIdx.x;
    const int lane = t & 63;
    const int w    = t >> 6;
    const int cb   = blockIdx.x >> 1;
    const int half = blockIdx.x & 1;
    const int row0 = (cb << CB_SHIFT) + half * 128;

    // stage Wt (2048 uint4 over 512 thr)
    {
        const uint4* Wg4 = (const uint4*)Wtg;
        #pragma unroll
        for (int it = 0; it < 4; ++it) {
            int idx = it * 512 + t;
            int row = idx >> 4, q = idx & 15;
            *(uint4*)&Wt[row * WT_STRIDE + q * 8] = Wg4[idx];
        }
    }
    if (t < 128) dhist[t] = 0;
    __syncthreads();
    // degree histogram of this block's half of the coarse bucket
    {
        int cnt = min(resv[cb], CAP);
        const int* seg = pairs + (size_t)cb * CAP;
        for (int i = t; i < cnt; i += 512) {
            int d8 = (seg[i] >> 17) & 255;
            if ((d8 >> 7) == half) atomicAdd(&dhist[d8 & 127], 1);
        }
    }
    __syncthreads();

    const int m  = lane & 15;
    const int ql = lane >> 4;
    const int arow = row0 + w * 16 + m;

    // A fragments direct from global x (fp32 -> fp16)
    half8 afrag[4];
    {
        const bool rv = arow < N;
        #pragma unroll
        for (int kc = 0; kc < 4; ++kc) {
            float4 f0 = make_float4(0.f, 0.f, 0.f, 0.f), f1 = f0;
            if (rv) {
                const float* xp = &x[(size_t)arow * CIN + kc * 32 + ql * 8];
                f0 = *(const float4*)xp;
                f1 = *(const float4*)(xp + 4);
            }
            half8 a;
            a[0] = (_Float16)f0.x; a[1] = (_Float16)f0.y;
            a[2] = (_Float16)f0.z; a[3] = (_Float16)f0.w;
            a[4] = (_Float16)f1.x; a[5] = (_Float16)f1.y;
            a[6] = (_Float16)f1.z; a[7] = (_Float16)f1.w;
            afrag[kc] = a;
        }
    }

    floatx4 acc[8];
    #pragma unroll
    for (int ct = 0; ct < 8; ++ct) acc[ct] = (floatx4){0.f, 0.f, 0.f, 0.f};

    #pragma unroll
    for (int kc = 0; kc < 4; ++kc) {
        #pragma unroll
        for (int ct = 0; ct < 8; ++ct) {
            half8 b = *(const half8*)&Wt[(ct * 16 + m) * WT_STRIDE + kc * 32 + ql * 8];
            acc[ct] = __builtin_amdgcn_mfma_f32_16x16x32_f16(afrag[kc], b, acc[ct], 0, 0, 0);
        }
    }

    // epilogue: rows grow = row0 + w*16 + ql*4 + r, col = ct*16 + m
    #pragma unroll
    for (int r = 0; r < 4; ++r) {
        int grow = row0 + w * 16 + ql * 4 + r;
        if (grow < N) {
            float dinv = rsqrtf((float)(dhist[grow & 127] + 1));
            #pragma unroll
            for (int ct = 0; ct < 8; ++ct)
                Hs[(size_t)grow * CCAT + ct * 16 + m] =
                    __float2half(acc[ct][r] * dinv);
        }
    }
}

// ---------------- 3: fused fine-sort + gather + finalize -------------------
// 4 blocks per coarse bucket (64-node quadrants), 512 thr = 8 waves.
// Filter segment by quadrant, fine-sort into per-node lists in LDS, wave
// gathers node PAIRS (2 interleaved accumulator sets): lane=(g:2)(chunk:4),
// uint4 load = 16B of edge j's row; 2x-unrolled edge loop keeps 4 gathers in
// flight per lane; packed-fp16 adds; butterfly over g; shared 16-lane
// epilogue (A on lanes 0-7, B on 8-15 via mu/ls symmetry).
__global__ __launch_bounds__(512) void sort_gather_kernel(
    const int* __restrict__ resv, const int* __restrict__ pairs,
    int* __restrict__ csrg,
    const __half* __restrict__ Hs,
    const float* __restrict__ bmu, const float* __restrict__ bls,
    const float* __restrict__ eps,
    float* __restrict__ out, int N, int NBC)
{
    __shared__ int hist[64];
    __shared__ int scs[64];
    __shared__ int rel[65];
    __shared__ int cur[64];
    __shared__ int ssort[SORT_CAP];

    const int t  = threadIdx.x, bx = blockIdx.x;
    const int cb = bx >> 2, q = bx & 3;
    const int nbase = (cb << CB_SHIFT) + q * 64;
    const int segcnt = min(resv[cb], CAP);
    const int* seg = pairs + (size_t)cb * CAP;

    if (t < 64) hist[t] = 0;
    __syncthreads();
    for (int i = t; i < segcnt; i += 512) {
        int d8 = (seg[i] >> 17) & 255;
        if ((d8 >> 6) == q) atomicAdd(&hist[d8 & 63], 1);
    }
    __syncthreads();
    if (t < 64) scs[t] = hist[t];
    __syncthreads();
    for (int off = 1; off < 64; off <<= 1) {
        int v = (t < 64 && t >= off) ? scs[t - off] : 0;
        __syncthreads();
        if (t < 64) scs[t] += v;
        __syncthreads();
    }
    if (t < 64) {
        int ex = scs[t] - hist[t];
        rel[t] = ex;
        cur[t] = ex;
    }
    if (t == 0) rel[64] = scs[63];
    __syncthreads();

    const int fcnt = rel[64];
    const bool in_lds = (fcnt <= SORT_CAP);
    for (int i = t; i < segcnt; i += 512) {
        int p = seg[i];
        int d8 = (p >> 17) & 255;
        if ((d8 >> 6) == q) {
            int pos = atomicAdd(&cur[d8 & 63], 1);
            int sval = p & 0x1FFFF;
            if (in_lds) ssort[pos] = sval;
            else if (pos < CSRG_CAP) csrg[(size_t)bx * CSRG_CAP + pos] = sval;
        }
    }
    __syncthreads();

    // ---- gather phase ----
    const int lane = t & 63;
    const int w    = t >> 6;           // wave 0..7, 8 nodes each
    const int ch   = lane & 15;        // 16-B chunk of the 256-B row
    const int g    = lane >> 4;        // edge group 0..3
    const int bc   = lane & 7;

    const float4* bmu4 = (const float4*)bmu;
    const float4* bls4 = (const float4*)bls;
    float4 bma = bmu4[bc * 2], bmb = bmu4[bc * 2 + 1];
    float4 bla = bls4[bc * 2], blb = bls4[bc * 2 + 1];

    const __half2 hz = __float2half2_rn(0.f);
    const int* csrb = csrg + (size_t)bx * CSRG_CAP;

    for (int ii = 0; ii < 4; ++ii) {
        const int nlA   = w * 8 + ii * 2;
        const int nodeA = nbase + nlA;
        const int nodeB = nodeA + 1;
        if (nodeA >= N) break;                 // wave-uniform
        const bool vB = nodeB < N;
        const int sA = rel[nlA],     dA = rel[nlA + 1] - sA;
        const int sB = rel[nlA + 1], dB = vB ? (rel[nlA + 2] - sB) : 0;

        __half2 a0 = hz, a1 = hz, a2 = hz, a3 = hz;   // node A
        __half2 c0 = hz, c1 = hz, c2 = hz, c3 = hz;   // node B
        if (g == 0) {   // self-loops
            uint4 raw = *(const uint4*)&Hs[(size_t)nodeA * CCAT + ch * 8];
            const __half2* p = (const __half2*)&raw;
            a0 = __hadd2(a0, p[0]); a1 = __hadd2(a1, p[1]);
            a2 = __hadd2(a2, p[2]); a3 = __hadd2(a3, p[3]);
            if (vB) {
                uint4 rb = *(const uint4*)&Hs[(size_t)nodeB * CCAT + ch * 8];
                const __half2* pq = (const __half2*)&rb;
                c0 = __hadd2(c0, pq[0]); c1 = __hadd2(c1, pq[1]);
                c2 = __hadd2(c2, pq[2]); c3 = __hadd2(c3, pq[3]);
            }
        }
        int jA = g, jB = g;
        while (jA < dA || jB < dB) {
            const bool a0v = jA < dA,     a1v = jA + 4 < dA;
            const bool b0v = jB < dB,     b1v = jB + 4 < dB;
            uint4 rA0, rA1, rB0, rB1;
            if (a0v) {
                int s = in_lds ? ssort[sA + jA] : csrb[sA + jA];
                rA0 = *(const uint4*)&Hs[(size_t)s * CCAT + ch * 8];
            }
            if (a1v) {
                int s = in_lds ? ssort[sA + jA + 4] : csrb[sA + jA + 4];
                rA1 = *(const uint4*)&Hs[(size_t)s * CCAT + ch * 8];
            }
            if (b0v) {
                int s = in_lds ? ssort[sB + jB] : csrb[sB + jB];
                rB0 = *(const uint4*)&Hs[(size_t)s * CCAT + ch * 8];
            }
            if (b1v) {
                int s = in_lds ? ssort[sB + jB + 4] : csrb[sB + jB + 4];
                rB1 = *(const uint4*)&Hs[(size_t)s * CCAT + ch * 8];
            }
            if (a0v) {
                const __half2* p = (const __half2*)&rA0;
                a0 = __hadd2(a0, p[0]); a1 = __hadd2(a1, p[1]);
                a2 = __hadd2(a2, p[2]); a3 = __hadd2(a3, p[3]);
            }
            if (a1v) {
                const __half2* p = (const __half2*)&rA1;
                a0 = __hadd2(a0, p[0]); a1 = __hadd2(a1, p[1]);
                a2 = __hadd2(a2, p[2]); a3 = __hadd2(a3, p[3]);
            }
            if (b0v) {
                const __half2* p = (const __half2*)&rB0;
                c0 = __hadd2(c0, p[0]); c1 = __hadd2(c1, p[1]);
                c2 = __hadd2(c2, p[2]); c3 = __hadd2(c3, p[3]);
            }
            if (b1v) {
                const __half2* p = (const __half2*)&rB1;
                c0 = __hadd2(c0, p[0]); c1 = __hadd2(c1, p[1]);
                c2 = __hadd2(c2, p[2]); c3 = __hadd2(c3, p[3]);
            }
            jA += 8; jB += 8;
        }
        // reduce over edge-group bits (lane bits 4-5), both nodes
        #pragma unroll
        for (int msk = 16; msk < 64; msk <<= 1) {
            a0 = __hadd2(a0, h2shfl_xor(a0, msk));
            a1 = __hadd2(a1, h2shfl_xor(a1, msk));
            a2 = __hadd2(a2, h2shfl_xor(a2, msk));
            a3 = __hadd2(a3, h2shfl_xor(a3, msk));
            c0 = __hadd2(c0, h2shfl_xor(c0, msk));
            c1 = __hadd2(c1, h2shfl_xor(c1, msk));
            c2 = __hadd2(c2, h2shfl_xor(c2, msk));
            c3 = __hadd2(c3, h2shfl_xor(c3, msk));
        }
        // mu/ls exchange symmetry
        __half2 x0 = h2shfl_xor(a0, 8), x1 = h2shfl_xor(a1, 8);
        __half2 x2 = h2shfl_xor(a2, 8), x3 = h2shfl_xor(a3, 8);
        __half2 y0 = h2shfl_xor(c0, 8), y1 = h2shfl_xor(c1, 8);
        __half2 y2 = h2shfl_xor(c2, 8), y3 = h2shfl_xor(c3, 8);

        if (lane < 16) {
            const bool isA = lane < 8;
            const int node = isA ? nodeA : nodeB;
            if (node < N) {
                const int deg = isA ? dA : dB;
                __half2 mu0 = isA ? a0 : y0, mu1 = isA ? a1 : y1;
                __half2 mu2 = isA ? a2 : y2, mu3 = isA ? a3 : y3;
                __half2 ls0 = isA ? x0 : c0, ls1 = isA ? x1 : c1;
                __half2 ls2 = isA ? x2 : c2, ls3 = isA ? x3 : c3;
                float dinv = rsqrtf((float)(deg + 1));
                float2 m0 = __half22float2(mu0), m1 = __half22float2(mu1);
                float2 m2 = __half22float2(mu2), m3 = __half22float2(mu3);
                float2 q0 = __half22float2(ls0), q1 = __half22float2(ls1);
                float2 q2 = __half22float2(ls2), q3 = __half22float2(ls3);
                const float4* eps4 = (const float4*)eps;
                float4 e0 = eps4[(size_t)node * 16 + bc * 2];
                float4 e1 = eps4[(size_t)node * 16 + bc * 2 + 1];
                float4 z0, z1;
                z0.x = (m0.x * dinv + bma.x) + e0.x * expf(fminf(q0.x * dinv + bla.x, MAX_LOGSTD));
                z0.y = (m0.y * dinv + bma.y) + e0.y * expf(fminf(q0.y * dinv + bla.y, MAX_LOGSTD));
                z0.z = (m1.x * dinv + bma.z) + e0.z * expf(fminf(q1.x * dinv + bla.z, MAX_LOGSTD));
                z0.w = (m1.y * dinv + bma.w) + e0.w * expf(fminf(q1.y * dinv + bla.w, MAX_LOGSTD));
                z1.x = (m2.x * dinv + bmb.x) + e1.x * expf(fminf(q2.x * dinv + blb.x, MAX_LOGSTD));
                z1.y = (m2.y * dinv + bmb.y) + e1.y * expf(fminf(q2.y * dinv + blb.y, MAX_LOGSTD));
                z1.z = (m3.x * dinv + bmb.z) + e1.z * expf(fminf(q3.x * dinv + blb.z, MAX_LOGSTD));
                z1.w = (m3.y * dinv + bmb.w) + e1.w * expf(fminf(q3.y * dinv + blb.w, MAX_LOGSTD));
                float4* out4 = (float4*)out;
                out4[(size_t)node * 16 + bc * 2]     = z0;
                out4[(size_t)node * 16 + bc * 2 + 1] = z1;
            }
        }
    }
}

extern "C" void kernel_launch(void* const* d_in, const int* in_sizes, int n_in,
                              void* d_out, int out_size, void* d_ws, size_t ws_size,
                              hipStream_t stream) {
    const float* x   = (const float*)d_in[0];
    const int*   ei  = (const int*)  d_in[1];   // [2, E] int32
    const float* Wmu = (const float*)d_in[2];
    const float* bmu = (const float*)d_in[3];
    const float* Wls = (const float*)d_in[4];
    const float* bls = (const float*)d_in[5];
    const float* eps = (const float*)d_in[6];

    const int E = in_sizes[1] / 2;
    const int N = in_sizes[6] / COUT;

    const int* src = ei;
    const int* dst = ei + E;

    const int NBC   = (N + 255) >> CB_SHIFT;                    // coarse buckets
    int chunk = (((E + PART_G - 1) / PART_G) + 3) & ~3;         // mult of 4
    if (chunk > CHUNK_MAX) chunk = CHUNK_MAX;                   // (E fixed: 3128)

    // workspace carve-up (all 512B-aligned)
    char* ws = (char*)d_ws;
    size_t off = 0;
    auto carve = [&](size_t bytes) {
        char* p = ws + off;
        off = (off + bytes + 511) & ~(size_t)511;
        return p;
    };
    int*    resv  = (int*)carve(512 * sizeof(int));
    __half* Wtg   = (__half*)carve((size_t)CCAT * CIN * sizeof(__half));
    int*    pairs = (int*)carve((size_t)NBC * CAP * sizeof(int));
    int*    csrg  = (int*)carve((size_t)NBC * 4 * CSRG_CAP * sizeof(int));
    __half* Hs    = (__half*)carve((size_t)N * CCAT * sizeof(__half));

    hipMemsetAsync(resv, 0, 512 * sizeof(int), stream);

    partition_kernel<<<PART_G, PART_T, 0, stream>>>(
        src, dst, resv, pairs, Wmu, Wls, Wtg, E, NBC, chunk);
    gemm_scale_kernel<<<NBC * 2, 512, 0, stream>>>(
        x, Wtg, resv, pairs, Hs, N, NBC);
    sort_gather_kernel<<<NBC * 4, 512, 0, stream>>>(
        resv, pairs, csrg, Hs, bmu, bls, eps, (float*)d_out, N, NBC);
}

// Round 2
// 240.200 us; speedup vs baseline: 1.0399x; 1.0399x over previous
//
#include <hip/hip_runtime.h>
#include <hip/hip_fp16.h>

// VGAE GCN encoder, pull-based. Pipeline (memset + 3 kernels):
//   1 partition  : single-pass CSR build. Coarse buckets = 256 nodes (NB=391),
//                  fixed-capacity segments (CAP=6144). Per block: LDS hist of
//                  its chunk -> one global atomicAdd per bucket reserves range
//                  -> rank+stage whole chunk in LDS -> bucket-major write
//                  (contiguous ~16-edge runs; coalesced). Packed int:
//                  (d&255)<<17 | s  (needs N < 2^17). Also preps W^T fp16.
//   2 gemm       : Hs = fp16((x @ [Wmu|Wls]) * dinv) MFMA 16x16x32_f16;
//                  2 blocks per coarse bucket; deg from filtered segment hist.
//   3 sort_gather: 8 blocks per coarse bucket (32-node OCTANTS, 256 thr =
//                  4 waves x 8 nodes): filter+fine-sort segment in LDS ->
//                  per-node src lists, wave gathers 2 nodes at a time (uint4
//                  row chunks, packed fp16 adds), shared 16-lane reparam
//                  epilogue. Octants double block count vs quadrants ->
//                  48.9 waves/CU offered, fills the 32-wave/CU cap.

#define CIN  128
#define CCAT 128
#define COUT 64
#define MAX_LOGSTD 10.0f

#define CB_SHIFT 8             // 256 nodes per coarse bucket
#define CAP      6144          // segment capacity (mean 4092, +32 sd)
#define PART_G   256
#define PART_T   512
#define CHUNK_MAX 6400         // LDS staging capacity (chunk = 6252)
#define SORT_CAP 896           // fine staging per octant (mean 512, +17 sd)
#define CSRG_CAP 1024          // global fallback region per fine block

typedef _Float16 half8 __attribute__((ext_vector_type(8)));
typedef float floatx4 __attribute__((ext_vector_type(4)));

#define WT_STRIDE 136          // fp16 elems; 272 B rows keep 16B alignment

__device__ __forceinline__ __half2 h2shfl_xor(__half2 v, int m) {
    union { __half2 h; int i; } u; u.h = v;
    u.i = __shfl_xor(u.i, m, 64);
    return u.h;
}

// ---------------- 1: single-pass partition + W^T prep ----------------------
__global__ __launch_bounds__(PART_T) void partition_kernel(
    const int* __restrict__ src, const int* __restrict__ dst,
    int* __restrict__ resv, int* __restrict__ pairs,
    const float* __restrict__ Wmu, const float* __restrict__ Wls,
    __half* __restrict__ Wtg, int E, int NBC, int chunk)
{
    __shared__ int hist[512];
    __shared__ int scs [512];
    __shared__ int lcur[512];
    __shared__ int base[512];
    __shared__ int ssort[CHUNK_MAX];
    __shared__ unsigned short sbuck[CHUNK_MAX];

    const int t = threadIdx.x, g = blockIdx.x;
    // W^T prep on first 32 blocks: Wtg[c*128+k] = W[k][c]
    if (g < 32) {
        int idx = g * PART_T + t;          // 0..16383
        int c = idx >> 7, k = idx & 127;
        float v = (c < 64) ? Wmu[k * COUT + c] : Wls[k * COUT + (c - 64)];
        Wtg[c * 128 + k] = __float2half(v);
    }
    hist[t] = 0;
    __syncthreads();

    const int lo  = g * chunk;
    const int hi  = min(E, lo + chunk);
    const int cnt = (hi > lo) ? (hi - lo) : 0;
    const bool al = ((((uintptr_t)(dst + lo)) | ((uintptr_t)(src + lo))) & 15) == 0;

    // pass 1: LDS histogram of dst buckets
    if (cnt > 0 && al) {
        const int nb4 = cnt >> 2;
        const int4* d4 = (const int4*)(dst + lo);
        for (int i = t; i < nb4; i += PART_T) {
            int4 d = d4[i];
            atomicAdd(&hist[d.x >> CB_SHIFT], 1);
            atomicAdd(&hist[d.y >> CB_SHIFT], 1);
            atomicAdd(&hist[d.z >> CB_SHIFT], 1);
            atomicAdd(&hist[d.w >> CB_SHIFT], 1);
        }
        for (int e = lo + (nb4 << 2) + t; e < hi; e += PART_T)
            atomicAdd(&hist[dst[e] >> CB_SHIFT], 1);
    } else if (cnt > 0) {
        for (int e = lo + t; e < hi; e += PART_T)
            atomicAdd(&hist[dst[e] >> CB_SHIFT], 1);
    }
    __syncthreads();

    // reserve global ranges; inclusive scan of hist for LDS slots
    scs[t]  = hist[t];
    lcur[t] = 0;
    base[t] = (t < NBC && hist[t] > 0) ? atomicAdd(&resv[t], hist[t]) : 0;
    __syncthreads();
    for (int off = 1; off < 512; off <<= 1) {
        int v = (t >= off) ? scs[t - off] : 0;
        __syncthreads();
        scs[t] += v;
        __syncthreads();
    }

    // pass 2: rank + stage packed edges into LDS (bucket-major)
    if (cnt > 0 && al) {
        const int nb4 = cnt >> 2;
        const int4* d4 = (const int4*)(dst + lo);
        const int4* s4 = (const int4*)(src + lo);
        for (int i = t; i < nb4; i += PART_T) {
            int4 d = d4[i]; int4 s = s4[i];
            int b, r, slot;
            b = d.x >> CB_SHIFT; r = atomicAdd(&lcur[b], 1); slot = scs[b] - hist[b] + r;
            ssort[slot] = ((d.x & 255) << 17) | s.x; sbuck[slot] = (unsigned short)b;
            b = d.y >> CB_SHIFT; r = atomicAdd(&lcur[b], 1); slot = scs[b] - hist[b] + r;
            ssort[slot] = ((d.y & 255) << 17) | s.y; sbuck[slot] = (unsigned short)b;
            b = d.z >> CB_SHIFT; r = atomicAdd(&lcur[b], 1); slot = scs[b] - hist[b] + r;
            ssort[slot] = ((d.z & 255) << 17) | s.z; sbuck[slot] = (unsigned short)b;
            b = d.w >> CB_SHIFT; r = atomicAdd(&lcur[b], 1); slot = scs[b] - hist[b] + r;
            ssort[slot] = ((d.w & 255) << 17) | s.w; sbuck[slot] = (unsigned short)b;
        }
        for (int e = lo + (nb4 << 2) + t; e < hi; e += PART_T) {
            int d = dst[e], s = src[e];
            int b = d >> CB_SHIFT;
            int r = atomicAdd(&lcur[b], 1);
            int slot = scs[b] - hist[b] + r;
            ssort[slot] = ((d & 255) << 17) | s; sbuck[slot] = (unsigned short)b;
        }
    } else if (cnt > 0) {
        for (int e = lo + t; e < hi; e += PART_T) {
            int d = dst[e], s = src[e];
            int b = d >> CB_SHIFT;
            int r = atomicAdd(&lcur[b], 1);
            int slot = scs[b] - hist[b] + r;
            ssort[slot] = ((d & 255) << 17) | s; sbuck[slot] = (unsigned short)b;
        }
    }
    __syncthreads();

    // pass 3: bucket-major write -> contiguous runs, coalesced
    for (int i = t; i < cnt; i += PART_T) {
        int b = sbuck[i];
        int gofs = base[b] + (i - (scs[b] - hist[b]));
        if (gofs < CAP)   // memory-safety clamp (statistically unreachable)
            pairs[(size_t)b * CAP + gofs] = ssort[i];
    }
}

// ---------------- 2: MFMA GEMM, 2 blocks per coarse bucket -----------------
// 512 thr = 8 waves x 16 rows = 128 rows/block. Wt staged from global fp16;
// A-frags direct from x; deg from filtered segment histogram.
__global__ __launch_bounds__(512) void gemm_scale_kernel(
    const float* __restrict__ x,
    const __half* __restrict__ Wtg,
    const int* __restrict__ resv, const int* __restrict__ pairs,
    __half* __restrict__ Hs, int N, int NBC)
{
    __shared__ _Float16 Wt[128 * WT_STRIDE];
    __shared__ int dhist[128];

    const int t    = threadIdx.x;
    const int lane = t & 63;
    const int w    = t >> 6;
    const int cb   = blockIdx.x >> 1;
    const int half = blockIdx.x & 1;
    const int row0 = (cb << CB_SHIFT) + half * 128;

    // stage Wt (2048 uint4 over 512 thr)
    {
        const uint4* Wg4 = (const uint4*)Wtg;
        #pragma unroll
        for (int it = 0; it < 4; ++it) {
            int idx = it * 512 + t;
            int row = idx >> 4, q = idx & 15;
            *(uint4*)&Wt[row * WT_STRIDE + q * 8] = Wg4[idx];
        }
    }
    if (t < 128) dhist[t] = 0;
    __syncthreads();
    // degree histogram of this block's half of the coarse bucket
    {
        int cnt = min(resv[cb], CAP);
        const int* seg = pairs + (size_t)cb * CAP;
        for (int i = t; i < cnt; i += 512) {
            int d8 = (seg[i] >> 17) & 255;
            if ((d8 >> 7) == half) atomicAdd(&dhist[d8 & 127], 1);
        }
    }
    __syncthreads();

    const int m  = lane & 15;
    const int ql = lane >> 4;
    const int arow = row0 + w * 16 + m;

    // A fragments direct from global x (fp32 -> fp16)
    half8 afrag[4];
    {
        const bool rv = arow < N;
        #pragma unroll
        for (int kc = 0; kc < 4; ++kc) {
            float4 f0 = make_float4(0.f, 0.f, 0.f, 0.f), f1 = f0;
            if (rv) {
                const float* xp = &x[(size_t)arow * CIN + kc * 32 + ql * 8];
                f0 = *(const float4*)xp;
                f1 = *(const float4*)(xp + 4);
            }
            half8 a;
            a[0] = (_Float16)f0.x; a[1] = (_Float16)f0.y;
            a[2] = (_Float16)f0.z; a[3] = (_Float16)f0.w;
            a[4] = (_Float16)f1.x; a[5] = (_Float16)f1.y;
            a[6] = (_Float16)f1.z; a[7] = (_Float16)f1.w;
            afrag[kc] = a;
        }
    }

    floatx4 acc[8];
    #pragma unroll
    for (int ct = 0; ct < 8; ++ct) acc[ct] = (floatx4){0.f, 0.f, 0.f, 0.f};

    #pragma unroll
    for (int kc = 0; kc < 4; ++kc) {
        #pragma unroll
        for (int ct = 0; ct < 8; ++ct) {
            half8 b = *(const half8*)&Wt[(ct * 16 + m) * WT_STRIDE + kc * 32 + ql * 8];
            acc[ct] = __builtin_amdgcn_mfma_f32_16x16x32_f16(afrag[kc], b, acc[ct], 0, 0, 0);
        }
    }

    // epilogue: rows grow = row0 + w*16 + ql*4 + r, col = ct*16 + m
    #pragma unroll
    for (int r = 0; r < 4; ++r) {
        int grow = row0 + w * 16 + ql * 4 + r;
        if (grow < N) {
            float dinv = rsqrtf((float)(dhist[grow & 127] + 1));
            #pragma unroll
            for (int ct = 0; ct < 8; ++ct)
                Hs[(size_t)grow * CCAT + ct * 16 + m] =
                    __float2half(acc[ct][r] * dinv);
        }
    }
}

// ---------------- 3: fused fine-sort + gather + finalize -------------------
// 8 blocks per coarse bucket (32-node octants), 256 thr = 4 waves x 8 nodes.
// Filter segment by octant, fine-sort into per-node lists in LDS, wave
// gathers node PAIRS (2 interleaved accumulator sets): lane=(g:2)(chunk:4),
// uint4 load = 16B of edge j's row; packed-fp16 adds; butterfly over g;
// shared 16-lane epilogue (A on lanes 0-7, B on 8-15 via mu/ls symmetry).
__global__ __launch_bounds__(256) void sort_gather_kernel(
    const int* __restrict__ resv, const int* __restrict__ pairs,
    int* __restrict__ csrg,
    const __half* __restrict__ Hs,
    const float* __restrict__ bmu, const float* __restrict__ bls,
    const float* __restrict__ eps,
    float* __restrict__ out, int N, int NBC)
{
    __shared__ int hist[32];
    __shared__ int scs[32];
    __shared__ int rel[33];
    __shared__ int cur[32];
    __shared__ int ssort[SORT_CAP];

    const int t  = threadIdx.x, bx = blockIdx.x;
    const int cb = bx >> 3, q = bx & 7;
    const int nbase = (cb << CB_SHIFT) + q * 32;
    const int segcnt = min(resv[cb], CAP);
    const int* seg = pairs + (size_t)cb * CAP;

    if (t < 32) hist[t] = 0;
    __syncthreads();
    for (int i = t; i < segcnt; i += 256) {
        int d8 = (seg[i] >> 17) & 255;
        if ((d8 >> 5) == q) atomicAdd(&hist[d8 & 31], 1);
    }
    __syncthreads();
    if (t < 32) scs[t] = hist[t];
    __syncthreads();
    for (int off = 1; off < 32; off <<= 1) {
        int v = (t < 32 && t >= off) ? scs[t - off] : 0;
        __syncthreads();
        if (t < 32) scs[t] += v;
        __syncthreads();
    }
    if (t < 32) {
        int ex = scs[t] - hist[t];
        rel[t] = ex;
        cur[t] = ex;
    }
    if (t == 0) rel[32] = scs[31];
    __syncthreads();

    const int fcnt = rel[32];
    const bool in_lds = (fcnt <= SORT_CAP);
    for (int i = t; i < segcnt; i += 256) {
        int p = seg[i];
        int d8 = (p >> 17) & 255;
        if ((d8 >> 5) == q) {
            int pos = atomicAdd(&cur[d8 & 31], 1);
            int sval = p & 0x1FFFF;
            if (in_lds) ssort[pos] = sval;
            else if (pos < CSRG_CAP) csrg[(size_t)bx * CSRG_CAP + pos] = sval;
        }
    }
    __syncthreads();

    // ---- gather phase ----
    const int lane = t & 63;
    const int w    = t >> 6;           // wave 0..3, 8 nodes each
    const int ch   = lane & 15;        // 16-B chunk of the 256-B row
    const int g    = lane >> 4;        // edge group 0..3
    const int bc   = lane & 7;

    const float4* bmu4 = (const float4*)bmu;
    const float4* bls4 = (const float4*)bls;
    float4 bma = bmu4[bc * 2], bmb = bmu4[bc * 2 + 1];
    float4 bla = bls4[bc * 2], blb = bls4[bc * 2 + 1];

    const __half2 hz = __float2half2_rn(0.f);
    const int* csrb = csrg + (size_t)bx * CSRG_CAP;

    for (int ii = 0; ii < 4; ++ii) {
        const int nlA   = w * 8 + ii * 2;
        const int nodeA = nbase + nlA;
        const int nodeB = nodeA + 1;
        if (nodeA >= N) break;                 // wave-uniform
        const bool vB = nodeB < N;
        const int sA = rel[nlA],     dA = rel[nlA + 1] - sA;
        const int sB = rel[nlA + 1], dB = vB ? (rel[nlA + 2] - sB) : 0;

        __half2 a0 = hz, a1 = hz, a2 = hz, a3 = hz;   // node A
        __half2 c0 = hz, c1 = hz, c2 = hz, c3 = hz;   // node B
        if (g == 0) {   // self-loops
            uint4 raw = *(const uint4*)&Hs[(size_t)nodeA * CCAT + ch * 8];
            const __half2* p = (const __half2*)&raw;
            a0 = __hadd2(a0, p[0]); a1 = __hadd2(a1, p[1]);
            a2 = __hadd2(a2, p[2]); a3 = __hadd2(a3, p[3]);
            if (vB) {
                uint4 rb = *(const uint4*)&Hs[(size_t)nodeB * CCAT + ch * 8];
                const __half2* pq = (const __half2*)&rb;
                c0 = __hadd2(c0, pq[0]); c1 = __hadd2(c1, pq[1]);
                c2 = __hadd2(c2, pq[2]); c3 = __hadd2(c3, pq[3]);
            }
        }
        int jA = g, jB = g;
        while (jA < dA || jB < dB) {
            const bool doA = jA < dA, doB = jB < dB;
            uint4 rA, rB;
            if (doA) {
                int s = in_lds ? ssort[sA + jA] : csrb[sA + jA];
                rA = *(const uint4*)&Hs[(size_t)s * CCAT + ch * 8];
            }
            if (doB) {
                int s = in_lds ? ssort[sB + jB] : csrb[sB + jB];
                rB = *(const uint4*)&Hs[(size_t)s * CCAT + ch * 8];
            }
            if (doA) {
                const __half2* p = (const __half2*)&rA;
                a0 = __hadd2(a0, p[0]); a1 = __hadd2(a1, p[1]);
                a2 = __hadd2(a2, p[2]); a3 = __hadd2(a3, p[3]);
                jA += 4;
            }
            if (doB) {
                const __half2* pq = (const __half2*)&rB;
                c0 = __hadd2(c0, pq[0]); c1 = __hadd2(c1, pq[1]);
                c2 = __hadd2(c2, pq[2]); c3 = __hadd2(c3, pq[3]);
                jB += 4;
            }
        }
        // reduce over edge-group bits (lane bits 4-5), both nodes
        #pragma unroll
        for (int msk = 16; msk < 64; msk <<= 1) {
            a0 = __hadd2(a0, h2shfl_xor(a0, msk));
            a1 = __hadd2(a1, h2shfl_xor(a1, msk));
            a2 = __hadd2(a2, h2shfl_xor(a2, msk));
            a3 = __hadd2(a3, h2shfl_xor(a3, msk));
            c0 = __hadd2(c0, h2shfl_xor(c0, msk));
            c1 = __hadd2(c1, h2shfl_xor(c1, msk));
            c2 = __hadd2(c2, h2shfl_xor(c2, msk));
            c3 = __hadd2(c3, h2shfl_xor(c3, msk));
        }
        // mu/ls exchange symmetry
        __half2 x0 = h2shfl_xor(a0, 8), x1 = h2shfl_xor(a1, 8);
        __half2 x2 = h2shfl_xor(a2, 8), x3 = h2shfl_xor(a3, 8);
        __half2 y0 = h2shfl_xor(c0, 8), y1 = h2shfl_xor(c1, 8);
        __half2 y2 = h2shfl_xor(c2, 8), y3 = h2shfl_xor(c3, 8);

        if (lane < 16) {
            const bool isA = lane < 8;
            const int node = isA ? nodeA : nodeB;
            if (node < N) {
                const int deg = isA ? dA : dB;
                __half2 mu0 = isA ? a0 : y0, mu1 = isA ? a1 : y1;
                __half2 mu2 = isA ? a2 : y2, mu3 = isA ? a3 : y3;
                __half2 ls0 = isA ? x0 : c0, ls1 = isA ? x1 : c1;
                __half2 ls2 = isA ? x2 : c2, ls3 = isA ? x3 : c3;
                float dinv = rsqrtf((float)(deg + 1));
                float2 m0 = __half22float2(mu0), m1 = __half22float2(mu1);
                float2 m2 = __half22float2(mu2), m3 = __half22float2(mu3);
                float2 q0 = __half22float2(ls0), q1 = __half22float2(ls1);
                float2 q2 = __half22float2(ls2), q3 = __half22float2(ls3);
                const float4* eps4 = (const float4*)eps;
                float4 e0 = eps4[(size_t)node * 16 + bc * 2];
                float4 e1 = eps4[(size_t)node * 16 + bc * 2 + 1];
                float4 z0, z1;
                z0.x = (m0.x * dinv + bma.x) + e0.x * expf(fminf(q0.x * dinv + bla.x, MAX_LOGSTD));
                z0.y = (m0.y * dinv + bma.y) + e0.y * expf(fminf(q0.y * dinv + bla.y, MAX_LOGSTD));
                z0.z = (m1.x * dinv + bma.z) + e0.z * expf(fminf(q1.x * dinv + bla.z, MAX_LOGSTD));
                z0.w = (m1.y * dinv + bma.w) + e0.w * expf(fminf(q1.y * dinv + bla.w, MAX_LOGSTD));
                z1.x = (m2.x * dinv + bmb.x) + e1.x * expf(fminf(q2.x * dinv + blb.x, MAX_LOGSTD));
                z1.y = (m2.y * dinv + bmb.y) + e1.y * expf(fminf(q2.y * dinv + blb.y, MAX_LOGSTD));
                z1.z = (m3.x * dinv + bmb.z) + e1.z * expf(fminf(q3.x * dinv + blb.z, MAX_LOGSTD));
                z1.w = (m3.y * dinv + bmb.w) + e1.w * expf(fminf(q3.y * dinv + blb.w, MAX_LOGSTD));
                float4* out4 = (float4*)out;
                out4[(size_t)node * 16 + bc * 2]     = z0;
                out4[(size_t)node * 16 + bc * 2 + 1] = z1;
            }
        }
    }
}

extern "C" void kernel_launch(void* const* d_in, const int* in_sizes, int n_in,
                              void* d_out, int out_size, void* d_ws, size_t ws_size,
                              hipStream_t stream) {
    const float* x   = (const float*)d_in[0];
    const int*   ei  = (const int*)  d_in[1];   // [2, E] int32
    const float* Wmu = (const float*)d_in[2];
    const float* bmu = (const float*)d_in[3];
    const float* Wls = (const float*)d_in[4];
    const float* bls = (const float*)d_in[5];
    const float* eps = (const float*)d_in[6];

    const int E = in_sizes[1] / 2;
    const int N = in_sizes[6] / COUT;

    const int* src = ei;
    const int* dst = ei + E;

    const int NBC   = (N + 255) >> CB_SHIFT;                    // coarse buckets
    int chunk = (((E + PART_G - 1) / PART_G) + 3) & ~3;         // mult of 4
    if (chunk > CHUNK_MAX) chunk = CHUNK_MAX;                   // (E fixed: 6252)

    // workspace carve-up (all 512B-aligned)
    char* ws = (char*)d_ws;
    size_t off = 0;
    auto carve = [&](size_t bytes) {
        char* p = ws + off;
        off = (off + bytes + 511) & ~(size_t)511;
        return p;
    };
    int*    resv  = (int*)carve(512 * sizeof(int));
    __half* Wtg   = (__half*)carve((size_t)CCAT * CIN * sizeof(__half));
    int*    pairs = (int*)carve((size_t)NBC * CAP * sizeof(int));
    int*    csrg  = (int*)carve((size_t)NBC * 8 * CSRG_CAP * sizeof(int));
    __half* Hs    = (__half*)carve((size_t)N * CCAT * sizeof(__half));

    hipMemsetAsync(resv, 0, 512 * sizeof(int), stream);

    partition_kernel<<<PART_G, PART_T, 0, stream>>>(
        src, dst, resv, pairs, Wmu, Wls, Wtg, E, NBC, chunk);
    gemm_scale_kernel<<<NBC * 2, 512, 0, stream>>>(
        x, Wtg, resv, pairs, Hs, N, NBC);
    sort_gather_kernel<<<NBC * 8, 256, 0, stream>>>(
        resv, pairs, csrg, Hs, bmu, bls, eps, (float*)d_out, N, NBC);
}

// Round 3
// 220.033 us; speedup vs baseline: 1.1352x; 1.0917x over previous
//
#include <hip/hip_runtime.h>
#include <hip/hip_fp16.h>

// VGAE GCN encoder, pull-based. Pipeline (memset + 3 kernels):
//   1 partition  : single-pass CSR build DIRECT TO FINE BUCKETS = 64 nodes
//                  (NBF=1563), fixed-capacity segments (FCAP=1536, 16 sd).
//                  Per block: LDS hist of its chunk over 1568 buckets -> one
//                  global atomicAdd per bucket reserves range -> blocked
//                  exclusive scan (4/thread + 512-wide) -> rank+stage chunk
//                  in LDS -> bucket-major write (coalesced runs). Packed int:
//                  (d&63)<<17 | s  (needs N < 2^17). Also preps W^T fp16.
//   2 gemm       : Hs = fp16((x @ [Wmu|Wls]) * dinv) MFMA 16x16x32_f16;
//                  128 rows/block = 2 fine buckets; deg hist scans exactly
//                  its own 2 segments, no filter.
//   3 sort_gather: 1 block per fine bucket (64 nodes, 256 thr = 4 waves x
//                  16 nodes): fine-sort OWN segment in LDS (no filter, no
//                  global fallback) -> per-node src lists, wave gathers 2
//                  nodes at a time (uint4 row chunks, packed fp16 adds),
//                  shared 16-lane reparam epilogue. eps via nontemporal
//                  loads, out via nontemporal stores (keep L2 for Hs).

#define CIN  128
#define CCAT 128
#define COUT 64
#define MAX_LOGSTD 10.0f

#define FB_SHIFT 6             // 64 nodes per fine bucket
#define NBF_MAX  1568          // LDS bucket-array bound (N <= 100352)
#define FCAP     1536          // fine segment capacity (mean 1024, +16 sd)
#define PART_G   256
#define PART_T   512
#define CHUNK_MAX 6400         // LDS staging capacity (chunk = 6252)

typedef _Float16 half8 __attribute__((ext_vector_type(8)));
typedef float floatx4 __attribute__((ext_vector_type(4)));
typedef float f32x4 __attribute__((ext_vector_type(4)));

#define WT_STRIDE 136          // fp16 elems; 272 B rows keep 16B alignment

__device__ __forceinline__ __half2 h2shfl_xor(__half2 v, int m) {
    union { __half2 h; int i; } u; u.h = v;
    u.i = __shfl_xor(u.i, m, 64);
    return u.h;
}

// ---------------- 1: single-pass fine partition + W^T prep -----------------
__global__ __launch_bounds__(PART_T) void partition_kernel(
    const int* __restrict__ src, const int* __restrict__ dst,
    int* __restrict__ resv, int* __restrict__ pairs,
    const float* __restrict__ Wmu, const float* __restrict__ Wls,
    __half* __restrict__ Wtg, int E, int NBF, int chunk)
{
    __shared__ int hist[NBF_MAX];       // counts -> exclusive scan (in place)
    __shared__ int lcur[NBF_MAX];
    __shared__ int base[NBF_MAX];
    __shared__ int wscan[PART_T];
    __shared__ int ssort[CHUNK_MAX];
    __shared__ unsigned short sbuck[CHUNK_MAX];

    const int t = threadIdx.x, g = blockIdx.x;
    // W^T prep on first 32 blocks: Wtg[c*128+k] = W[k][c]
    if (g < 32) {
        int idx = g * PART_T + t;          // 0..16383
        int c = idx >> 7, k = idx & 127;
        float v = (c < 64) ? Wmu[k * COUT + c] : Wls[k * COUT + (c - 64)];
        Wtg[c * 128 + k] = __float2half(v);
    }
    for (int i = t; i < NBF_MAX; i += PART_T) { hist[i] = 0; lcur[i] = 0; }
    __syncthreads();

    const int lo  = g * chunk;
    const int hi  = min(E, lo + chunk);
    const int cnt = (hi > lo) ? (hi - lo) : 0;
    const bool al = ((((uintptr_t)(dst + lo)) | ((uintptr_t)(src + lo))) & 15) == 0;

    // pass 1: LDS histogram of dst fine buckets
    if (cnt > 0 && al) {
        const int nb4 = cnt >> 2;
        const int4* d4 = (const int4*)(dst + lo);
        for (int i = t; i < nb4; i += PART_T) {
            int4 d = d4[i];
            atomicAdd(&hist[d.x >> FB_SHIFT], 1);
            atomicAdd(&hist[d.y >> FB_SHIFT], 1);
            atomicAdd(&hist[d.z >> FB_SHIFT], 1);
            atomicAdd(&hist[d.w >> FB_SHIFT], 1);
        }
        for (int e = lo + (nb4 << 2) + t; e < hi; e += PART_T)
            atomicAdd(&hist[dst[e] >> FB_SHIFT], 1);
    } else if (cnt > 0) {
        for (int e = lo + t; e < hi; e += PART_T)
            atomicAdd(&hist[dst[e] >> FB_SHIFT], 1);
    }
    __syncthreads();

    // reserve global ranges per fine bucket
    for (int b = t; b < NBF; b += PART_T) {
        int h = hist[b];
        base[b] = (h > 0) ? atomicAdd(&resv[b], h) : 0;
    }

    // blocked exclusive scan of hist (4 entries/thread + 512-wide scan);
    // written back into hist in place.
    int h0, h1, h2, h3;
    const int i0 = t << 2;
    h0 = (i0     < NBF_MAX) ? hist[i0]     : 0;
    h1 = (i0 + 1 < NBF_MAX) ? hist[i0 + 1] : 0;
    h2 = (i0 + 2 < NBF_MAX) ? hist[i0 + 2] : 0;
    h3 = (i0 + 3 < NBF_MAX) ? hist[i0 + 3] : 0;
    const int tsum = h0 + h1 + h2 + h3;
    wscan[t] = tsum;
    __syncthreads();
    for (int off = 1; off < PART_T; off <<= 1) {
        int v = (t >= off) ? wscan[t - off] : 0;
        __syncthreads();
        wscan[t] += v;
        __syncthreads();
    }
    {
        int ex = wscan[t] - tsum;
        if (i0     < NBF_MAX) hist[i0]     = ex;
        if (i0 + 1 < NBF_MAX) hist[i0 + 1] = ex + h0;
        if (i0 + 2 < NBF_MAX) hist[i0 + 2] = ex + h0 + h1;
        if (i0 + 3 < NBF_MAX) hist[i0 + 3] = ex + h0 + h1 + h2;
    }
    __syncthreads();

    // pass 2: rank + stage packed edges into LDS (bucket-major)
    if (cnt > 0 && al) {
        const int nb4 = cnt >> 2;
        const int4* d4 = (const int4*)(dst + lo);
        const int4* s4 = (const int4*)(src + lo);
        for (int i = t; i < nb4; i += PART_T) {
            int4 d = d4[i]; int4 s = s4[i];
            int b, r, slot;
            b = d.x >> FB_SHIFT; r = atomicAdd(&lcur[b], 1); slot = hist[b] + r;
            ssort[slot] = ((d.x & 63) << 17) | s.x; sbuck[slot] = (unsigned short)b;
            b = d.y >> FB_SHIFT; r = atomicAdd(&lcur[b], 1); slot = hist[b] + r;
            ssort[slot] = ((d.y & 63) << 17) | s.y; sbuck[slot] = (unsigned short)b;
            b = d.z >> FB_SHIFT; r = atomicAdd(&lcur[b], 1); slot = hist[b] + r;
            ssort[slot] = ((d.z & 63) << 17) | s.z; sbuck[slot] = (unsigned short)b;
            b = d.w >> FB_SHIFT; r = atomicAdd(&lcur[b], 1); slot = hist[b] + r;
            ssort[slot] = ((d.w & 63) << 17) | s.w; sbuck[slot] = (unsigned short)b;
        }
        for (int e = lo + (nb4 << 2) + t; e < hi; e += PART_T) {
            int d = dst[e], s = src[e];
            int b = d >> FB_SHIFT;
            int r = atomicAdd(&lcur[b], 1);
            int slot = hist[b] + r;
            ssort[slot] = ((d & 63) << 17) | s; sbuck[slot] = (unsigned short)b;
        }
    } else if (cnt > 0) {
        for (int e = lo + t; e < hi; e += PART_T) {
            int d = dst[e], s = src[e];
            int b = d >> FB_SHIFT;
            int r = atomicAdd(&lcur[b], 1);
            int slot = hist[b] + r;
            ssort[slot] = ((d & 63) << 17) | s; sbuck[slot] = (unsigned short)b;
        }
    }
    __syncthreads();

    // pass 3: bucket-major write -> contiguous runs, coalesced
    for (int i = t; i < cnt; i += PART_T) {
        int b = sbuck[i];
        int gofs = base[b] + (i - hist[b]);
        if (gofs < FCAP)   // memory-safety clamp (16 sd, statistically unreachable)
            pairs[(size_t)b * FCAP + gofs] = ssort[i];
    }
}

// ---------------- 2: MFMA GEMM, 128 rows = 2 fine buckets per block --------
// 512 thr = 8 waves x 16 rows. Wt staged from global fp16; A-frags direct
// from x; deg hist scans exactly this block's 2 fine segments (no filter).
__global__ __launch_bounds__(512) void gemm_scale_kernel(
    const float* __restrict__ x,
    const __half* __restrict__ Wtg,
    const int* __restrict__ resv, const int* __restrict__ pairs,
    __half* __restrict__ Hs, int N, int NBF)
{
    __shared__ _Float16 Wt[128 * WT_STRIDE];
    __shared__ int dhist[128];

    const int t    = threadIdx.x;
    const int lane = t & 63;
    const int w    = t >> 6;
    const int fb0  = blockIdx.x << 1;          // first fine bucket
    const int row0 = fb0 << FB_SHIFT;          // 128-aligned

    // stage Wt (2048 uint4 over 512 thr)
    {
        const uint4* Wg4 = (const uint4*)Wtg;
        #pragma unroll
        for (int it = 0; it < 4; ++it) {
            int idx = it * 512 + t;
            int row = idx >> 4, q = idx & 15;
            *(uint4*)&Wt[row * WT_STRIDE + q * 8] = Wg4[idx];
        }
    }
    if (t < 128) dhist[t] = 0;
    __syncthreads();
    // degree histogram: scan own 2 fine segments
    #pragma unroll
    for (int sb = 0; sb < 2; ++sb) {
        int fb = fb0 + sb;
        if (fb < NBF) {
            int cnt = min(resv[fb], FCAP);
            const int* seg = pairs + (size_t)fb * FCAP;
            for (int i = t; i < cnt; i += 512)
                atomicAdd(&dhist[sb * 64 + ((seg[i] >> 17) & 63)], 1);
        }
    }
    __syncthreads();

    const int m  = lane & 15;
    const int ql = lane >> 4;
    const int arow = row0 + w * 16 + m;

    // A fragments direct from global x (fp32 -> fp16)
    half8 afrag[4];
    {
        const bool rv = arow < N;
        #pragma unroll
        for (int kc = 0; kc < 4; ++kc) {
            float4 f0 = make_float4(0.f, 0.f, 0.f, 0.f), f1 = f0;
            if (rv) {
                const float* xp = &x[(size_t)arow * CIN + kc * 32 + ql * 8];
                f0 = *(const float4*)xp;
                f1 = *(const float4*)(xp + 4);
            }
            half8 a;
            a[0] = (_Float16)f0.x; a[1] = (_Float16)f0.y;
            a[2] = (_Float16)f0.z; a[3] = (_Float16)f0.w;
            a[4] = (_Float16)f1.x; a[5] = (_Float16)f1.y;
            a[6] = (_Float16)f1.z; a[7] = (_Float16)f1.w;
            afrag[kc] = a;
        }
    }

    floatx4 acc[8];
    #pragma unroll
    for (int ct = 0; ct < 8; ++ct) acc[ct] = (floatx4){0.f, 0.f, 0.f, 0.f};

    #pragma unroll
    for (int kc = 0; kc < 4; ++kc) {
        #pragma unroll
        for (int ct = 0; ct < 8; ++ct) {
            half8 b = *(const half8*)&Wt[(ct * 16 + m) * WT_STRIDE + kc * 32 + ql * 8];
            acc[ct] = __builtin_amdgcn_mfma_f32_16x16x32_f16(afrag[kc], b, acc[ct], 0, 0, 0);
        }
    }

    // epilogue: rows grow = row0 + w*16 + ql*4 + r, col = ct*16 + m
    #pragma unroll
    for (int r = 0; r < 4; ++r) {
        int grow = row0 + w * 16 + ql * 4 + r;
        if (grow < N) {
            float dinv = rsqrtf((float)(dhist[grow & 127] + 1));
            #pragma unroll
            for (int ct = 0; ct < 8; ++ct)
                Hs[(size_t)grow * CCAT + ct * 16 + m] =
                    __float2half(acc[ct][r] * dinv);
        }
    }
}

// ---------------- 3: fused fine-sort + gather + finalize -------------------
// 1 block per fine bucket (64 nodes, 256 thr = 4 waves x 16 nodes). Fine-sort
// OWN segment in LDS (no filter, no fallback) -> per-node src lists, wave
// gathers node PAIRS (2 interleaved accumulator sets): lane=(g:2)(chunk:4),
// uint4 load = 16B of edge j's row; packed-fp16 adds; butterfly over g;
// shared 16-lane epilogue (A on lanes 0-7, B on 8-15 via mu/ls symmetry).
__global__ __launch_bounds__(256) void sort_gather_kernel(
    const int* __restrict__ resv, const int* __restrict__ pairs,
    const __half* __restrict__ Hs,
    const float* __restrict__ bmu, const float* __restrict__ bls,
    const float* __restrict__ eps,
    float* __restrict__ out, int N, int NBF)
{
    __shared__ int hist[64];
    __shared__ int scs[64];
    __shared__ int rel[65];
    __shared__ int cur[64];
    __shared__ int ssort[FCAP];

    const int t  = threadIdx.x, bx = blockIdx.x;
    const int nbase = bx << FB_SHIFT;
    const int segcnt = min(resv[bx], FCAP);
    const int* seg = pairs + (size_t)bx * FCAP;

    if (t < 64) hist[t] = 0;
    __syncthreads();
    for (int i = t; i < segcnt; i += 256)
        atomicAdd(&hist[(seg[i] >> 17) & 63], 1);
    __syncthreads();
    if (t < 64) scs[t] = hist[t];
    __syncthreads();
    for (int off = 1; off < 64; off <<= 1) {
        int v = (t < 64 && t >= off) ? scs[t - off] : 0;
        __syncthreads();
        if (t < 64) scs[t] += v;
        __syncthreads();
    }
    if (t < 64) {
        int ex = scs[t] - hist[t];
        rel[t] = ex;
        cur[t] = ex;
    }
    if (t == 0) rel[64] = scs[63];
    __syncthreads();

    for (int i = t; i < segcnt; i += 256) {
        int p = seg[i];
        int pos = atomicAdd(&cur[(p >> 17) & 63], 1);
        ssort[pos] = p & 0x1FFFF;
    }
    __syncthreads();

    // ---- gather phase ----
    const int lane = t & 63;
    const int w    = t >> 6;           // wave 0..3, 16 nodes each
    const int ch   = lane & 15;        // 16-B chunk of the 256-B row
    const int g    = lane >> 4;        // edge group 0..3
    const int bc   = lane & 7;

    const float4* bmu4 = (const float4*)bmu;
    const float4* bls4 = (const float4*)bls;
    float4 bma = bmu4[bc * 2], bmb = bmu4[bc * 2 + 1];
    float4 bla = bls4[bc * 2], blb = bls4[bc * 2 + 1];

    const __half2 hz = __float2half2_rn(0.f);

    for (int ii = 0; ii < 8; ++ii) {
        const int nlA   = w * 16 + ii * 2;
        const int nodeA = nbase + nlA;
        const int nodeB = nodeA + 1;
        if (nodeA >= N) break;                 // wave-uniform
        const bool vB = nodeB < N;
        const int sA = rel[nlA],     dA = rel[nlA + 1] - sA;
        const int sB = rel[nlA + 1], dB = vB ? (rel[nlA + 2] - sB) : 0;

        __half2 a0 = hz, a1 = hz, a2 = hz, a3 = hz;   // node A
        __half2 c0 = hz, c1 = hz, c2 = hz, c3 = hz;   // node B
        if (g == 0) {   // self-loops
            uint4 raw = *(const uint4*)&Hs[(size_t)nodeA * CCAT + ch * 8];
            const __half2* p = (const __half2*)&raw;
            a0 = __hadd2(a0, p[0]); a1 = __hadd2(a1, p[1]);
            a2 = __hadd2(a2, p[2]); a3 = __hadd2(a3, p[3]);
            if (vB) {
                uint4 rb = *(const uint4*)&Hs[(size_t)nodeB * CCAT + ch * 8];
                const __half2* pq = (const __half2*)&rb;
                c0 = __hadd2(c0, pq[0]); c1 = __hadd2(c1, pq[1]);
                c2 = __hadd2(c2, pq[2]); c3 = __hadd2(c3, pq[3]);
            }
        }
        int jA = g, jB = g;
        while (jA < dA || jB < dB) {
            const bool doA = jA < dA, doB = jB < dB;
            uint4 rA, rB;
            if (doA) {
                int s = ssort[sA + jA];
                rA = *(const uint4*)&Hs[(size_t)s * CCAT + ch * 8];
            }
            if (doB) {
                int s = ssort[sB + jB];
                rB = *(const uint4*)&Hs[(size_t)s * CCAT + ch * 8];
            }
            if (doA) {
                const __half2* p = (const __half2*)&rA;
                a0 = __hadd2(a0, p[0]); a1 = __hadd2(a1, p[1]);
                a2 = __hadd2(a2, p[2]); a3 = __hadd2(a3, p[3]);
                jA += 4;
            }
            if (doB) {
                const __half2* pq = (const __half2*)&rB;
                c0 = __hadd2(c0, pq[0]); c1 = __hadd2(c1, pq[1]);
                c2 = __hadd2(c2, pq[2]); c3 = __hadd2(c3, pq[3]);
                jB += 4;
            }
        }
        // reduce over edge-group bits (lane bits 4-5), both nodes
        #pragma unroll
        for (int msk = 16; msk < 64; msk <<= 1) {
            a0 = __hadd2(a0, h2shfl_xor(a0, msk));
            a1 = __hadd2(a1, h2shfl_xor(a1, msk));
            a2 = __hadd2(a2, h2shfl_xor(a2, msk));
            a3 = __hadd2(a3, h2shfl_xor(a3, msk));
            c0 = __hadd2(c0, h2shfl_xor(c0, msk));
            c1 = __hadd2(c1, h2shfl_xor(c1, msk));
            c2 = __hadd2(c2, h2shfl_xor(c2, msk));
            c3 = __hadd2(c3, h2shfl_xor(c3, msk));
        }
        // mu/ls exchange symmetry
        __half2 x0 = h2shfl_xor(a0, 8), x1 = h2shfl_xor(a1, 8);
        __half2 x2 = h2shfl_xor(a2, 8), x3 = h2shfl_xor(a3, 8);
        __half2 y0 = h2shfl_xor(c0, 8), y1 = h2shfl_xor(c1, 8);
        __half2 y2 = h2shfl_xor(c2, 8), y3 = h2shfl_xor(c3, 8);

        if (lane < 16) {
            const bool isA = lane < 8;
            const int node = isA ? nodeA : nodeB;
            if (node < N) {
                const int deg = isA ? dA : dB;
                __half2 mu0 = isA ? a0 : y0, mu1 = isA ? a1 : y1;
                __half2 mu2 = isA ? a2 : y2, mu3 = isA ? a3 : y3;
                __half2 ls0 = isA ? x0 : c0, ls1 = isA ? x1 : c1;
                __half2 ls2 = isA ? x2 : c2, ls3 = isA ? x3 : c3;
                float dinv = rsqrtf((float)(deg + 1));
                float2 m0 = __half22float2(mu0), m1 = __half22float2(mu1);
                float2 m2 = __half22float2(mu2), m3 = __half22float2(mu3);
                float2 q0 = __half22float2(ls0), q1 = __half22float2(ls1);
                float2 q2 = __half22float2(ls2), q3 = __half22float2(ls3);
                const f32x4* eps4 = (const f32x4*)eps;
                f32x4 e0v = __builtin_nontemporal_load(eps4 + (size_t)node * 16 + bc * 2);
                f32x4 e1v = __builtin_nontemporal_load(eps4 + (size_t)node * 16 + bc * 2 + 1);
                f32x4 z0, z1;
                z0[0] = (m0.x * dinv + bma.x) + e0v[0] * expf(fminf(q0.x * dinv + bla.x, MAX_LOGSTD));
                z0[1] = (m0.y * dinv + bma.y) + e0v[1] * expf(fminf(q0.y * dinv + bla.y, MAX_LOGSTD));
                z0[2] = (m1.x * dinv + bma.z) + e0v[2] * expf(fminf(q1.x * dinv + bla.z, MAX_LOGSTD));
                z0[3] = (m1.y * dinv + bma.w) + e0v[3] * expf(fminf(q1.y * dinv + bla.w, MAX_LOGSTD));
                z1[0] = (m2.x * dinv + bmb.x) + e1v[0] * expf(fminf(q2.x * dinv + blb.x, MAX_LOGSTD));
                z1[1] = (m2.y * dinv + bmb.y) + e1v[1] * expf(fminf(q2.y * dinv + blb.y, MAX_LOGSTD));
                z1[2] = (m3.x * dinv + bmb.z) + e1v[2] * expf(fminf(q3.x * dinv + blb.z, MAX_LOGSTD));
                z1[3] = (m3.y * dinv + bmb.w) + e1v[3] * expf(fminf(q3.y * dinv + blb.w, MAX_LOGSTD));
                f32x4* out4 = (f32x4*)out;
                __builtin_nontemporal_store(z0, out4 + (size_t)node * 16 + bc * 2);
                __builtin_nontemporal_store(z1, out4 + (size_t)node * 16 + bc * 2 + 1);
            }
        }
    }
}

extern "C" void kernel_launch(void* const* d_in, const int* in_sizes, int n_in,
                              void* d_out, int out_size, void* d_ws, size_t ws_size,
                              hipStream_t stream) {
    const float* x   = (const float*)d_in[0];
    const int*   ei  = (const int*)  d_in[1];   // [2, E] int32
    const float* Wmu = (const float*)d_in[2];
    const float* bmu = (const float*)d_in[3];
    const float* Wls = (const float*)d_in[4];
    const float* bls = (const float*)d_in[5];
    const float* eps = (const float*)d_in[6];

    const int E = in_sizes[1] / 2;
    const int N = in_sizes[6] / COUT;

    const int* src = ei;
    const int* dst = ei + E;

    const int NBF = (N + 63) >> FB_SHIFT;                       // fine buckets
    int chunk = (((E + PART_G - 1) / PART_G) + 3) & ~3;         // mult of 4
    if (chunk > CHUNK_MAX) chunk = CHUNK_MAX;                   // (E fixed: 6252)

    // workspace carve-up (all 512B-aligned)
    char* ws = (char*)d_ws;
    size_t off = 0;
    auto carve = [&](size_t bytes) {
        char* p = ws + off;
        off = (off + bytes + 511) & ~(size_t)511;
        return p;
    };
    int*    resv  = (int*)carve(2048 * sizeof(int));
    __half* Wtg   = (__half*)carve((size_t)CCAT * CIN * sizeof(__half));
    int*    pairs = (int*)carve((size_t)NBF_MAX * FCAP * sizeof(int));
    __half* Hs    = (__half*)carve((size_t)N * CCAT * sizeof(__half));

    hipMemsetAsync(resv, 0, 2048 * sizeof(int), stream);

    partition_kernel<<<PART_G, PART_T, 0, stream>>>(
        src, dst, resv, pairs, Wmu, Wls, Wtg, E, NBF, chunk);
    gemm_scale_kernel<<<(NBF + 1) >> 1, 512, 0, stream>>>(
        x, Wtg, resv, pairs, Hs, N, NBF);
    sort_gather_kernel<<<NBF, 256, 0, stream>>>(
        resv, pairs, Hs, bmu, bls, eps, (float*)d_out, N, NBF);
}